// Round 11
// baseline (220.607 us; speedup 1.0000x reference)
//
#include <hip/hip_runtime.h>
#include <hip/hip_bf16.h>

#define BB 4
#define CC 64
#define OO 64
#define NN 32768
#define TT 4
#define KK 9
#define PADW 4
#define SIGMA 0.05f
#define EPS_BN 1e-5f

typedef __attribute__((ext_vector_type(8))) short bf16x8;
typedef __attribute__((ext_vector_type(4))) float f32x4;

__device__ __forceinline__ unsigned short f2bf(float f) {
  __hip_bfloat16 h = __float2bfloat16(f);
  return *reinterpret_cast<unsigned short*>(&h);
}
__device__ __forceinline__ unsigned int pkbf(float a, float b) {
  float2 t; t.x = a; t.y = b;
  __hip_bfloat162 h = __float22bfloat162_rn(t);
  unsigned int r;
  __builtin_memcpy(&r, &h, 4);
  return r;
}
// direct global->LDS 16B async copy (per-lane global src, wave-uniform LDS base)
__device__ __forceinline__ void gload16(const void* g, void* l) {
  __builtin_amdgcn_global_load_lds(
      (const __attribute__((address_space(1))) void*)g,
      (__attribute__((address_space(3))) void*)l,
      16, 0, 0);
}

// ---------------------------------------------------------------------------
// Merged prep: blocks [0,2048) transpose, [2048,2560) ind/mc t-slice,
// [2560,2596) conv-weight fragment prep, [2596] zero-page.
// ---------------------------------------------------------------------------
__global__ __launch_bounds__(256) void prep_kernel(
    const float* __restrict__ inp, unsigned short* __restrict__ xTb,
    const float* __restrict__ cw,  unsigned short* __restrict__ W4,
    const int*   __restrict__ ind, const float* __restrict__ mc,
    int* __restrict__ indT, float* __restrict__ mcT,
    float* __restrict__ zpage)
{
  __shared__ float xt[64][65];
  const int bid = blockIdx.x;
  const int tid = threadIdx.x;

  if (bid < 2048) {
    // --- transpose input (B,C,N) f32 -> (B,N,C) bf16
    const int n0 = (bid & 511) * 64;
    const int b  = bid >> 9;
    {
      int nl = tid & 63, c4 = tid >> 6;
      #pragma unroll
      for (int i = 0; i < 16; ++i) {
        int c = c4 * 16 + i;
        xt[c][nl] = inp[((size_t)(b*CC + c))*NN + n0 + nl];
      }
    }
    __syncthreads();
    {
      int nl = tid >> 2, cq = tid & 3;
      unsigned int pk[8];
      #pragma unroll
      for (int i = 0; i < 8; ++i) {
        int c = cq*16 + i*2;
        pk[i] = pkbf(xt[c][nl], xt[c+1][nl]);
      }
      unsigned int* dst = (unsigned int*)(xTb + (((size_t)b*NN) + n0 + nl)*CC + cq*16);
      ((int4*)dst)[0] = make_int4((int)pk[0],(int)pk[1],(int)pk[2],(int)pk[3]);
      ((int4*)dst)[1] = make_int4((int)pk[4],(int)pk[5],(int)pk[6],(int)pk[7]);
    }
  } else if (bid < 2560) {
    // --- t-slice ind (B,N,T)->indT (T,B,N), mc (B,3,N,T)->mcT (T,B,3,N)
    const int id = bid - 2048;
    const int n  = (id & 127) * 256 + tid;
    const int b  = id >> 7;
    int4 iv = *(const int4*)(ind + ((size_t)b*NN + n)*TT);
    indT[((size_t)(0*BB + b))*NN + n] = iv.x;
    indT[((size_t)(1*BB + b))*NN + n] = iv.y;
    indT[((size_t)(2*BB + b))*NN + n] = iv.z;
    indT[((size_t)(3*BB + b))*NN + n] = iv.w;
    #pragma unroll
    for (int d = 0; d < 3; ++d) {
      float4 mv = *(const float4*)(mc + (((size_t)(b*3 + d))*NN + n)*TT);
      mcT[((size_t)((0*BB + b)*3 + d))*NN + n] = mv.x;
      mcT[((size_t)((1*BB + b)*3 + d))*NN + n] = mv.y;
      mcT[((size_t)((2*BB + b)*3 + d))*NN + n] = mv.z;
      mcT[((size_t)((3*BB + b)*3 + d))*NN + n] = mv.w;
    }
  } else if (bid < 2596) {
    // --- conv weights (T,O,C,K) f32 -> fragment-order bf16
    const int id = bid - 2560;      // 0..35
    const int k = id % KK;
    const int t = id / KK;
    for (int u = tid; u < OO*CC; u += 256) {
      int o = u >> 6, c = u & 63;
      int ow = o >> 5, ot = (o >> 4) & 1, l15 = o & 15;
      int frag = c >> 5, q = (c >> 3) & 3, j = c & 7;
      float wv = cw[(((size_t)(t*OO + o))*CC + c)*KK + k];
      W4[(size_t)(t*9+k)*4096 + ow*2048 + ot*1024 + frag*512 + l15*32 + q*8 + j]
          = f2bf(wv);
    }
  } else {
    // --- zero page for padded gather rows
    zpage[tid] = 0.f;
  }
}

// ---------------------------------------------------------------------------
// Conv: n-tile 256, 4 waves.  ids/mcs staged -> barrier -> gathers via
// global_load_lds (direct-to-LDS, pre-swizzled global source chunk) ->
// wgl VALU overlaps flight -> barrier (drains vmcnt) -> MFMA.
// LDS layout identical to the proven register-staged version.
// ---------------------------------------------------------------------------
__global__ __launch_bounds__(256, 3) void conv_kernel(
    const unsigned short* __restrict__ xTb,  // (B,N,C) bf16
    const float* __restrict__ mcT,           // (T,B,3,N)
    const int*   __restrict__ indT,          // (T,B,N)
    const unsigned short* __restrict__ W4,   // fragment-order bf16
    const float* __restrict__ zpage,         // 1KB zeros
    unsigned short* __restrict__ Y,          // (T,B,N,O) bf16
    float* __restrict__ cpart2)              // (256 to, 2, 2048 slots)
{
  const int n0  = blockIdx.x * 256;
  const int b   = blockIdx.y;
  const int t   = blockIdx.z;
  const int tid = threadIdx.x;
  const int lane = tid & 63;
  const int w    = tid >> 6;
  const int l15  = lane & 15;
  const int q    = lane >> 4;
  const int ow   = w & 1;     // o half  (32 o's)
  const int nw   = w >> 1;    // n half  (128 n's)

  __shared__ short xg[264*64];       // exact 128B rows, chunk-XOR swizzled
  __shared__ float wgl[256][10];     // window weights
  __shared__ float mcs[3][268];      // coords for this t, zero-padded
  __shared__ int   ids[268];         // window indices for this t

  // --- stage ids + coords, coalesced from t-sliced layouts
  for (int u = tid; u < 264; u += 256) {
    int m = n0 + u - PADW;
    bool v = (m >= 0) && (m < NN);
    ids[u] = v ? indT[((size_t)(t*BB + b))*NN + m] : -1;
    #pragma unroll
    for (int d = 0; d < 3; ++d)
      mcs[d][u] = v ? mcT[((size_t)((t*BB + b)*3 + d))*NN + m] : 0.f;
  }
  __syncthreads();

  // --- issue direct-to-LDS gathers (33 wave-uniform 1KB chunks)
  #pragma unroll
  for (int i = 0; i < 9; ++i) {
    int chunk = w + 4*i;            // 0..35, uniform per wave
    if (chunk < 33) {
      int u = chunk*64 + lane;
      int p = u >> 3, c = u & 7;
      int idx = ids[p];
      int sg = c ^ (p & 7);         // pre-swizzled source chunk
      const void* src = (idx >= 0)
          ? (const void*)(xTb + ((size_t)b*NN + idx)*CC + sg*8)
          : (const void*)((const unsigned short*)zpage + c*8);
      gload16(src, &xg[chunk*512]);
    }
  }

  // --- window weights (row nl = tid, all 9 k's) — overlaps gather flight
  {
    int nl = tid;
    float cx = mcs[0][nl+4], cy = mcs[1][nl+4], cz = mcs[2][nl+4];
    #pragma unroll
    for (int k = 0; k < KK; ++k) {
      float dx = mcs[0][nl+k]-cx, dy = mcs[1][nl+k]-cy, dz = mcs[2][nl+k]-cz;
      float s2 = dx*dx + dy*dy + dz*dz;
      float r = (s2 > 0.f) ? sqrtf(s2) : 0.f;
      wgl[nl][k] = fmaxf(1.f - r*(1.f/SIGMA), 0.f);
    }
  }
  __syncthreads();   // drains gload vmcnt -> xg ready

  // --- MFMA loop
  const unsigned short* Wt = W4 + (size_t)t*9*4096 + ow*2048 + (l15*4 + q)*8;
  const f32x4 Z = {0.f, 0.f, 0.f, 0.f};
  f32x4 fin[2][8];
  #pragma unroll
  for (int ot = 0; ot < 2; ++ot)
    #pragma unroll
    for (int ns = 0; ns < 8; ++ns) fin[ot][ns] = Z;

  for (int k = 0; k < KK; ++k) {
    const unsigned short* Wk = Wt + (size_t)k*4096;
    bf16x8 af[2][2];
    #pragma unroll
    for (int ot = 0; ot < 2; ++ot) {
      af[ot][0] = *(const bf16x8*)(Wk + ot*1024);
      af[ot][1] = *(const bf16x8*)(Wk + ot*1024 + 512);
    }
    #pragma unroll
    for (int ns = 0; ns < 8; ++ns) {
      int nl = nw*128 + ns*16 + l15;
      int p  = nl + k;
      const short* row = &xg[p << 6];
      int sw = p & 7;
      bf16x8 b0 = *(const bf16x8*)(row + ((q ^ sw) << 3));
      bf16x8 b1 = *(const bf16x8*)(row + (((4 + q) ^ sw) << 3));
      float wgt = wgl[nl][k];
      #pragma unroll
      for (int ot = 0; ot < 2; ++ot) {
        f32x4 d = __builtin_amdgcn_mfma_f32_16x16x32_bf16(af[ot][0], b0, Z, 0, 0, 0);
        d = __builtin_amdgcn_mfma_f32_16x16x32_bf16(af[ot][1], b1, d, 0, 0, 0);
        fin[ot][ns] += wgt * d;
      }
    }
  }

  // --- register epilogue 1: direct Y stores, (T,B,N,O)
  #pragma unroll
  for (int ns = 0; ns < 8; ++ns) {
    int nl = nw*128 + ns*16 + l15;
    size_t row = (((size_t)t*BB + b)*NN + n0 + nl)*OO;
    #pragma unroll
    for (int ot = 0; ot < 2; ++ot) {
      uint2 pk2;
      pk2.x = pkbf(fin[ot][ns][0], fin[ot][ns][1]);
      pk2.y = pkbf(fin[ot][ns][2], fin[ot][ns][3]);
      *(uint2*)(Y + row + ow*32 + ot*16 + q*4) = pk2;
    }
  }

  // --- register epilogue 2: stats via shfl butterfly (width 16)
  float sv[16];
  #pragma unroll
  for (int ot = 0; ot < 2; ++ot)
    #pragma unroll
    for (int r = 0; r < 4; ++r) {
      float a = 0.f, qs = 0.f;
      #pragma unroll
      for (int ns = 0; ns < 8; ++ns) {
        float v = fin[ot][ns][r];
        a += v; qs += v*v;
      }
      sv[ot*4+r] = a; sv[8+ot*4+r] = qs;
    }
  #pragma unroll
  for (int msk = 1; msk < 16; msk <<= 1) {
    #pragma unroll
    for (int i = 0; i < 16; ++i) sv[i] += __shfl_xor(sv[i], msk, 16);
  }
  if (l15 == 0) {
    int slot4 = ((b*128 + (int)blockIdx.x) << 2) | w;   // [0,2048)
    #pragma unroll
    for (int ot = 0; ot < 2; ++ot)
      #pragma unroll
      for (int r = 0; r < 4; ++r) {
        int o = ow*32 + ot*16 + q*4 + r;
        cpart2[((size_t)((t*64 + o)*2 + 0))*2048 + slot4] = sv[ot*4+r];
        cpart2[((size_t)((t*64 + o)*2 + 1))*2048 + slot4] = sv[8+ot*4+r];
      }
  }
}

// ---------------------------------------------------------------------------
// Reduce conv partials -> per-(t,o) scale/shift.  Grid 256 = (t,o).
// ---------------------------------------------------------------------------
__global__ __launch_bounds__(256) void bnparam_kernel(
    const float* __restrict__ cpart2,  // (256,2,2048)
    const float* __restrict__ gam,
    const float* __restrict__ bet,
    float* __restrict__ ss)            // (T*O,2)
{
  const int to = blockIdx.x;
  const int tid = threadIdx.x;
  __shared__ float r1[256], r2[256];
  const float* p1 = cpart2 + (size_t)to*2*2048;
  const float* p2 = p1 + 2048;
  float s1 = 0.f, s2 = 0.f;
  for (int i = tid*4; i < 2048; i += 1024) {
    float4 a = *(const float4*)(p1 + i);
    float4 c = *(const float4*)(p2 + i);
    s1 += a.x + a.y + a.z + a.w;
    s2 += c.x + c.y + c.z + c.w;
  }
  r1[tid] = s1; r2[tid] = s2;
  __syncthreads();
  for (int st = 128; st > 0; st >>= 1) {
    if (tid < st) { r1[tid] += r1[tid+st]; r2[tid] += r2[tid+st]; }
    __syncthreads();
  }
  if (tid == 0) {
    const float inv = 1.f / (float)(BB * NN);
    float mean = r1[0] * inv;
    float var  = r2[0] * inv - mean * mean;
    float sc = gam[to] * rsqrtf(var + EPS_BN);
    ss[to*2 + 0] = sc;
    ss[to*2 + 1] = bet[to] - mean * sc;
  }
}

// ---------------------------------------------------------------------------
// wfuse: fold conv-BN into fusion weights.
//   fbp[o]  = fb[o] + sum_c fw[o,c]*sh[c]
//   FWB[rk*2048 + ow*1024 + ot*512 + l15*32 + q*8 + j] = bf16(fw[o,c]*sc[c])
// 1 block, 256 threads.
// ---------------------------------------------------------------------------
__global__ __launch_bounds__(256) void wfuse_kernel(
    const float* __restrict__ fw,     // (O,256)
    const float* __restrict__ fb,     // (O)
    const float* __restrict__ ss,     // (256,2) sc/sh
    float* __restrict__ fbp,          // (O)
    unsigned short* __restrict__ FWB) // (16384) bf16 fragment-order
{
  const int tid = threadIdx.x;
  {
    int o = tid >> 2, c0 = (tid & 3) * 64;
    float s = 0.f;
    for (int c = c0; c < c0 + 64; ++c)
      s += fw[o*256 + c] * ss[c*2 + 1];
    s += __shfl_xor(s, 1);
    s += __shfl_xor(s, 2);
    if ((tid & 3) == 0) fbp[o] = fb[o] + s;
  }
  for (int e = tid; e < 16384; e += 256) {
    int rk  = e >> 11;
    int ow  = (e >> 10) & 1;
    int ot  = (e >> 9) & 1;
    int l15 = (e >> 5) & 15;
    int cj  = e & 31;                      // q*8 + j
    int o = ow*32 + ot*16 + l15;
    int c = (rk >> 1)*64 + (rk & 1)*32 + cj;
    FWB[e] = f2bf(fw[o*256 + c] * ss[c*2]);
  }
}

// ---------------------------------------------------------------------------
// Fusion: n-tile 128, K=256 in 4 quarter-rounds.  Staging via
// global_load_lds (pre-swizzled source); FWB fragments prefetched before
// the barrier.  lb(256,4) (proven).  Slot stats.
// ---------------------------------------------------------------------------
__global__ __launch_bounds__(256, 4) void fusion_kernel(
    const unsigned short* __restrict__ Y,    // (T,B,N,O) bf16
    const int*   __restrict__ rind,          // (B,N,T)
    const unsigned short* __restrict__ FWB,  // pre-scaled fragment weights
    const float* __restrict__ fbp,           // (O) folded bias
    float* __restrict__ out,                 // (B,O,N) pre-BN
    float* __restrict__ fpart2)              // (O, 2, 4096 slots)
{
  const int n0  = blockIdx.x * 128;
  const int b   = blockIdx.y;
  const int tid = threadIdx.x;
  const int lane = tid & 63;
  const int w    = tid >> 6;
  const int l15  = lane & 15;
  const int q    = lane >> 4;
  const int ow   = w & 1;
  const int nw   = w >> 1;

  __shared__ short zg[128*64];      // exact 128B rows, chunk-XOR swizzled

  // prefetch reindices: thread covers rows n = (tid>>3) + 32*i (all 4 t)
  int4 rg[4];
  #pragma unroll
  for (int i = 0; i < 4; ++i) {
    int n = (tid >> 3) + 32*i;
    rg[i] = *(const int4*)(rind + ((size_t)b*NN + n0 + n)*TT);
  }

  f32x4 fin[2][4];
  #pragma unroll
  for (int ot = 0; ot < 2; ++ot)
    #pragma unroll
    for (int ns = 0; ns < 4; ++ns) fin[ot][ns] = (f32x4){0.f,0.f,0.f,0.f};

  #pragma unroll
  for (int r = 0; r < 4; ++r) {     // K-quarter == t index
    if (r) __syncthreads();         // consumers of round r-1 done
    // issue direct-to-LDS gathers (16 wave-uniform 1KB chunks)
    #pragma unroll
    for (int i = 0; i < 4; ++i) {
      int chunk = w + 4*i;          // 0..15
      int u = chunk*64 + lane;
      int n = u >> 3, c = u & 7;
      int rn = (r == 0) ? rg[i].x : (r == 1) ? rg[i].y
             : (r == 2) ? rg[i].z : rg[i].w;
      int sg = c ^ (n & 7);         // pre-swizzled source chunk
      gload16(Y + (((size_t)r*BB + b)*NN + rn)*OO + sg*8, &zg[chunk*512]);
    }
    // prefetch this round's weight fragments (independent of zg)
    bf16x8 af[2][2];
    #pragma unroll
    for (int kk = 0; kk < 2; ++kk) {
      const unsigned short* wp = FWB + (r*2+kk)*2048 + ow*1024 + (l15*4 + q)*8;
      af[kk][0] = *(const bf16x8*)(wp);
      af[kk][1] = *(const bf16x8*)(wp + 512);
    }
    __syncthreads();                // drains gload vmcnt -> zg ready

    #pragma unroll
    for (int kk = 0; kk < 2; ++kk) {
      #pragma unroll
      for (int ns = 0; ns < 4; ++ns) {
        int nl = nw*64 + ns*16 + l15;
        int ch = (kk*4 + q) ^ (nl & 7);
        bf16x8 bfr = *(const bf16x8*)&zg[(nl << 6) + (ch << 3)];
        #pragma unroll
        for (int ot = 0; ot < 2; ++ot)
          fin[ot][ns] = __builtin_amdgcn_mfma_f32_16x16x32_bf16(af[kk][ot], bfr, fin[ot][ns], 0, 0, 0);
      }
    }
  }

  // epilogue: folded bias, coalesced stores, stats butterfly + slot stores
  float sv[16];
  #pragma unroll
  for (int ot = 0; ot < 2; ++ot)
    #pragma unroll
    for (int r2 = 0; r2 < 4; ++r2) {
      int o = ow*32 + ot*16 + q*4 + r2;
      float bias = fbp[o];
      float* dst = out + ((size_t)(b*OO + o))*NN + n0 + nw*64;
      float a = 0.f, qs = 0.f;
      #pragma unroll
      for (int ns = 0; ns < 4; ++ns) {
        float v = fin[ot][ns][r2] + bias;
        dst[ns*16 + l15] = v;
        a += v; qs += v*v;
      }
      sv[ot*4+r2] = a; sv[8+ot*4+r2] = qs;
    }
  #pragma unroll
  for (int msk = 1; msk < 16; msk <<= 1) {
    #pragma unroll
    for (int i = 0; i < 16; ++i) sv[i] += __shfl_xor(sv[i], msk, 16);
  }
  if (l15 == 0) {
    int slot4 = ((b*256 + (int)blockIdx.x) << 2) | w;   // [0,4096)
    #pragma unroll
    for (int ot = 0; ot < 2; ++ot)
      #pragma unroll
      for (int r2 = 0; r2 < 4; ++r2) {
        int o = ow*32 + ot*16 + q*4 + r2;
        fpart2[((size_t)(o*2 + 0))*4096 + slot4] = sv[ot*4+r2];
        fpart2[((size_t)(o*2 + 1))*4096 + slot4] = sv[8+ot*4+r2];
      }
  }
}

// ---------------------------------------------------------------------------
// Fold fusion partials -> per-o scale/shift.  Grid 64 = o.
// ---------------------------------------------------------------------------
__global__ __launch_bounds__(256) void freduce_kernel(
    const float* __restrict__ fpart2,  // (64,2,4096)
    const float* __restrict__ fg,
    const float* __restrict__ fbeta,
    float* __restrict__ fss)
{
  const int o = blockIdx.x;
  const int tid = threadIdx.x;
  __shared__ float r1[256], r2[256];
  const float* p1 = fpart2 + (size_t)o*2*4096;
  const float* p2 = p1 + 4096;
  float s1 = 0.f, s2 = 0.f;
  for (int i = tid*4; i < 4096; i += 1024) {
    float4 a = *(const float4*)(p1 + i);
    float4 c = *(const float4*)(p2 + i);
    s1 += a.x + a.y + a.z + a.w;
    s2 += c.x + c.y + c.z + c.w;
  }
  r1[tid] = s1; r2[tid] = s2;
  __syncthreads();
  for (int st = 128; st > 0; st >>= 1) {
    if (tid < st) { r1[tid] += r1[tid+st]; r2[tid] += r2[tid+st]; }
    __syncthreads();
  }
  if (tid == 0) {
    const float inv = 1.f / (float)(BB * NN);
    float mean = r1[0] * inv;
    float var  = r2[0] * inv - mean * mean;
    float sc = fg[o] * rsqrtf(var + EPS_BN);
    fss[o*2 + 0] = sc;
    fss[o*2 + 1] = fbeta[o] - mean * sc;
  }
}

// ---------------------------------------------------------------------------
// fusion BN + relu, in place (float4 vectorized)
// ---------------------------------------------------------------------------
__global__ __launch_bounds__(256) void final_kernel(
    float* __restrict__ out, const float* __restrict__ fss)
{
  const int base = blockIdx.x * 2048 + threadIdx.x * 4;
  #pragma unroll
  for (int s = 0; s < 2; ++s) {
    int e = base + s * 1024;
    int o2 = (e >> 15) & 63;
    float sc = fss[o2*2 + 0];
    float sh = fss[o2*2 + 1];
    float4 v = *(float4*)(out + e);
    v.x = fmaxf(v.x*sc + sh, 0.f);
    v.y = fmaxf(v.y*sc + sh, 0.f);
    v.z = fmaxf(v.z*sc + sh, 0.f);
    v.w = fmaxf(v.w*sc + sh, 0.f);
    *(float4*)(out + e) = v;
  }
}

// ---------------------------------------------------------------------------
extern "C" void kernel_launch(void* const* d_in, const int* in_sizes, int n_in,
                              void* d_out, int out_size, void* d_ws, size_t ws_size,
                              hipStream_t stream) {
  const float* inp  = (const float*)d_in[0];
  const float* mc   = (const float*)d_in[1];
  const int*   ind  = (const int*)  d_in[2];
  const int*   rind = (const int*)  d_in[3];
  const float* cw   = (const float*)d_in[4];
  const float* bg   = (const float*)d_in[5];
  const float* bb   = (const float*)d_in[6];
  const float* fw   = (const float*)d_in[7];
  const float* fb   = (const float*)d_in[8];
  const float* fg   = (const float*)d_in[9];
  const float* fbt  = (const float*)d_in[10];

  // ws: [0,2048) convss | [2048,2560) fss | [3072,3328) fbp | [4096,5120) zpage |
  //     [8192, 8192+64MiB) Y | [+2MiB) fpart2 | [+32KiB) FWB
  char* ws = (char*)d_ws;
  float* convss = (float*)(ws + 0);
  float* fss    = (float*)(ws + 2048);
  float* fbp    = (float*)(ws + 3072);
  float* zpage  = (float*)(ws + 4096);
  unsigned short* Y = (unsigned short*)(ws + 8192);          // 67,108,864 B
  float* fpart2 = (float*)(ws + 8192 + 67108864);            // 2 MiB
  unsigned short* FWB = (unsigned short*)(ws + 8192 + 67108864 + 2097152); // 32 KiB

  // scratch in d_out (all dead before fusion writes it):
  char* ob = (char*)d_out;
  unsigned short* xTb = (unsigned short*)ob;                 // 16,777,216 B
  unsigned short* W4  = (unsigned short*)(ob + 16777216);    //    294,912 B
  float* cpart2 = (float*)(ob + 17072128);                   //  4,194,304 B
  int*   indT   = (int*)  (ob + 21266432);                   //  2,097,152 B
  float* mcT    = (float*)(ob + 23363584);                   //  6,291,456 B  (ends 29,655,040 < 32MiB)
  float* out = (float*)d_out;

  prep_kernel<<<2597, 256, 0, stream>>>(inp, xTb, cw, W4, ind, mc, indT, mcT, zpage);

  dim3 gc(NN/256, BB, TT);
  conv_kernel<<<gc, 256, 0, stream>>>(xTb, mcT, indT, W4, zpage, Y, cpart2);

  bnparam_kernel<<<256, 256, 0, stream>>>(cpart2, bg, bb, convss);

  wfuse_kernel<<<1, 256, 0, stream>>>(fw, fb, convss, fbp, FWB);

  dim3 gf(NN/128, BB);
  fusion_kernel<<<gf, 256, 0, stream>>>(Y, rind, FWB, fbp, out, fpart2);

  freduce_kernel<<<OO, 256, 0, stream>>>(fpart2, fg, fbt, fss);

  final_kernel<<<(BB*OO*NN)/2048, 256, 0, stream>>>(out, fss);
}

// Round 12
// 213.097 us; speedup vs baseline: 1.0352x; 1.0352x over previous
//
#include <hip/hip_runtime.h>
#include <hip/hip_bf16.h>

#define BB 4
#define CC 64
#define OO 64
#define NN 32768
#define TT 4
#define KK 9
#define PADW 4
#define SIGMA 0.05f
#define EPS_BN 1e-5f

typedef __attribute__((ext_vector_type(8))) short bf16x8;
typedef __attribute__((ext_vector_type(4))) float f32x4;

__device__ __forceinline__ unsigned short f2bf(float f) {
  __hip_bfloat16 h = __float2bfloat16(f);
  return *reinterpret_cast<unsigned short*>(&h);
}
__device__ __forceinline__ unsigned int pkbf(float a, float b) {
  float2 t; t.x = a; t.y = b;
  __hip_bfloat162 h = __float22bfloat162_rn(t);
  unsigned int r;
  __builtin_memcpy(&r, &h, 4);
  return r;
}

// ---------------------------------------------------------------------------
// Merged prep: blocks [0,2048) transpose, [2048,2560) ind/mc t-slice,
// [2560,2596) conv-weight fragment prep.
// ---------------------------------------------------------------------------
__global__ __launch_bounds__(256) void prep_kernel(
    const float* __restrict__ inp, unsigned short* __restrict__ xTb,
    const float* __restrict__ cw,  unsigned short* __restrict__ W4,
    const int*   __restrict__ ind, const float* __restrict__ mc,
    int* __restrict__ indT, float* __restrict__ mcT)
{
  __shared__ float xt[64][65];
  const int bid = blockIdx.x;
  const int tid = threadIdx.x;

  if (bid < 2048) {
    // --- transpose input (B,C,N) f32 -> (B,N,C) bf16
    const int n0 = (bid & 511) * 64;
    const int b  = bid >> 9;
    {
      int nl = tid & 63, c4 = tid >> 6;
      #pragma unroll
      for (int i = 0; i < 16; ++i) {
        int c = c4 * 16 + i;
        xt[c][nl] = inp[((size_t)(b*CC + c))*NN + n0 + nl];
      }
    }
    __syncthreads();
    {
      int nl = tid >> 2, cq = tid & 3;
      unsigned int pk[8];
      #pragma unroll
      for (int i = 0; i < 8; ++i) {
        int c = cq*16 + i*2;
        pk[i] = pkbf(xt[c][nl], xt[c+1][nl]);
      }
      unsigned int* dst = (unsigned int*)(xTb + (((size_t)b*NN) + n0 + nl)*CC + cq*16);
      ((int4*)dst)[0] = make_int4((int)pk[0],(int)pk[1],(int)pk[2],(int)pk[3]);
      ((int4*)dst)[1] = make_int4((int)pk[4],(int)pk[5],(int)pk[6],(int)pk[7]);
    }
  } else if (bid < 2560) {
    // --- t-slice ind (B,N,T)->indT (T,B,N), mc (B,3,N,T)->mcT (T,B,3,N)
    const int id = bid - 2048;
    const int n  = (id & 127) * 256 + tid;
    const int b  = id >> 7;
    int4 iv = *(const int4*)(ind + ((size_t)b*NN + n)*TT);
    indT[((size_t)(0*BB + b))*NN + n] = iv.x;
    indT[((size_t)(1*BB + b))*NN + n] = iv.y;
    indT[((size_t)(2*BB + b))*NN + n] = iv.z;
    indT[((size_t)(3*BB + b))*NN + n] = iv.w;
    #pragma unroll
    for (int d = 0; d < 3; ++d) {
      float4 mv = *(const float4*)(mc + (((size_t)(b*3 + d))*NN + n)*TT);
      mcT[((size_t)((0*BB + b)*3 + d))*NN + n] = mv.x;
      mcT[((size_t)((1*BB + b)*3 + d))*NN + n] = mv.y;
      mcT[((size_t)((2*BB + b)*3 + d))*NN + n] = mv.z;
      mcT[((size_t)((3*BB + b)*3 + d))*NN + n] = mv.w;
    }
  } else {
    // --- conv weights (T,O,C,K) f32 -> fragment-order bf16
    const int id = bid - 2560;      // 0..35
    const int k = id % KK;
    const int t = id / KK;
    for (int u = tid; u < OO*CC; u += 256) {
      int o = u >> 6, c = u & 63;
      int ow = o >> 5, ot = (o >> 4) & 1, l15 = o & 15;
      int frag = c >> 5, q = (c >> 3) & 3, j = c & 7;
      float wv = cw[(((size_t)(t*OO + o))*CC + c)*KK + k];
      W4[(size_t)(t*9+k)*4096 + ow*2048 + ot*1024 + frag*512 + l15*32 + q*8 + j]
          = f2bf(wv);
    }
  }
}

// ---------------------------------------------------------------------------
// Conv: n-tile 256, 4 waves.  XCD-partitioned grid: all blocks of batch b
// map to XCD pair {2b,2b+1} (flat%8 = XCD round-robin assumption), so each
// XCD's 4MB L2 holds exactly b's 4MB xTb slice -> gathers become L2 hits.
// Proven r10 register-staged body otherwise.
// ---------------------------------------------------------------------------
__global__ __launch_bounds__(256, 3) void conv_kernel(
    const unsigned short* __restrict__ xTb,  // (B,N,C) bf16
    const float* __restrict__ mcT,           // (T,B,3,N)
    const int*   __restrict__ indT,          // (T,B,N)
    const unsigned short* __restrict__ W4,   // fragment-order bf16
    unsigned short* __restrict__ Y,          // (T,B,N,O) bf16
    float* __restrict__ cpart2)              // (256 to, 2, 2048 slots)
{
  // XCD-aware decode: xcd = flat%8 carries b; sub enumerates (t,x) per b.
  const int flat = blockIdx.x;              // [0,2048)
  const int xcd  = flat & 7;
  const int b    = xcd >> 1;
  const int sub  = (xcd & 1) + 2*(flat >> 3);  // [0,512)
  const int t    = sub >> 7;
  const int x    = sub & 127;
  const int n0   = x * 256;
  const int tid = threadIdx.x;
  const int lane = tid & 63;
  const int w    = tid >> 6;
  const int l15  = lane & 15;
  const int q    = lane >> 4;
  const int ow   = w & 1;     // o half  (32 o's)
  const int nw   = w >> 1;    // n half  (128 n's)

  __shared__ short xg[264*64];       // exact 128B rows, chunk-XOR swizzled
  __shared__ float wgl[256][10];     // window weights
  __shared__ float mcs[3][268];      // coords for this t, zero-padded
  __shared__ int   ids[268];         // window indices for this t

  // --- stage ids + coords, coalesced from t-sliced layouts
  for (int u = tid; u < 264; u += 256) {
    int m = n0 + u - PADW;
    bool v = (m >= 0) && (m < NN);
    ids[u] = v ? indT[((size_t)(t*BB + b))*NN + m] : -1;
    #pragma unroll
    for (int d = 0; d < 3; ++d)
      mcs[d][u] = v ? mcT[((size_t)((t*BB + b)*3 + d))*NN + m] : 0.f;
  }
  __syncthreads();

  // --- batch-issue gathers (idx from LDS; 264 rows x 8 chunks = 2112)
  int4 g[9];
  #pragma unroll
  for (int i = 0; i < 9; ++i) {
    int u = tid + 256*i;
    g[i] = make_int4(0,0,0,0);
    if (u < 2112) {
      int p = u >> 3, s = u & 7;
      int idx = ids[p];
      if (idx >= 0)
        g[i] = *(const int4*)(xTb + ((size_t)b*NN + idx)*CC + s*8);
    }
  }

  // --- window weights (row nl = tid, all 9 k's) — overlaps gather flight
  {
    int nl = tid;
    float cx = mcs[0][nl+4], cy = mcs[1][nl+4], cz = mcs[2][nl+4];
    #pragma unroll
    for (int k = 0; k < KK; ++k) {
      float dx = mcs[0][nl+k]-cx, dy = mcs[1][nl+k]-cy, dz = mcs[2][nl+k]-cz;
      float s2 = dx*dx + dy*dy + dz*dz;
      float r = (s2 > 0.f) ? sqrtf(s2) : 0.f;
      wgl[nl][k] = fmaxf(1.f - r*(1.f/SIGMA), 0.f);
    }
  }

  // --- commit gather to swizzled LDS
  #pragma unroll
  for (int i = 0; i < 9; ++i) {
    int u = tid + 256*i;
    if (u < 2112) {
      int p = u >> 3, s = u & 7;
      *(int4*)&xg[(p << 6) + ((s ^ (p & 7)) << 3)] = g[i];
    }
  }
  __syncthreads();

  // --- MFMA loop
  const unsigned short* Wt = W4 + (size_t)t*9*4096 + ow*2048 + (l15*4 + q)*8;
  const f32x4 Z = {0.f, 0.f, 0.f, 0.f};
  f32x4 fin[2][8];
  #pragma unroll
  for (int ot = 0; ot < 2; ++ot)
    #pragma unroll
    for (int ns = 0; ns < 8; ++ns) fin[ot][ns] = Z;

  for (int k = 0; k < KK; ++k) {
    const unsigned short* Wk = Wt + (size_t)k*4096;
    bf16x8 af[2][2];
    #pragma unroll
    for (int ot = 0; ot < 2; ++ot) {
      af[ot][0] = *(const bf16x8*)(Wk + ot*1024);
      af[ot][1] = *(const bf16x8*)(Wk + ot*1024 + 512);
    }
    #pragma unroll
    for (int ns = 0; ns < 8; ++ns) {
      int nl = nw*128 + ns*16 + l15;
      int p  = nl + k;
      const short* row = &xg[p << 6];
      int sw = p & 7;
      bf16x8 b0 = *(const bf16x8*)(row + ((q ^ sw) << 3));
      bf16x8 b1 = *(const bf16x8*)(row + (((4 + q) ^ sw) << 3));
      float wgt = wgl[nl][k];
      #pragma unroll
      for (int ot = 0; ot < 2; ++ot) {
        f32x4 d = __builtin_amdgcn_mfma_f32_16x16x32_bf16(af[ot][0], b0, Z, 0, 0, 0);
        d = __builtin_amdgcn_mfma_f32_16x16x32_bf16(af[ot][1], b1, d, 0, 0, 0);
        fin[ot][ns] += wgt * d;
      }
    }
  }

  // --- register epilogue 1: direct Y stores, (T,B,N,O)
  #pragma unroll
  for (int ns = 0; ns < 8; ++ns) {
    int nl = nw*128 + ns*16 + l15;
    size_t row = (((size_t)t*BB + b)*NN + n0 + nl)*OO;
    #pragma unroll
    for (int ot = 0; ot < 2; ++ot) {
      uint2 pk2;
      pk2.x = pkbf(fin[ot][ns][0], fin[ot][ns][1]);
      pk2.y = pkbf(fin[ot][ns][2], fin[ot][ns][3]);
      *(uint2*)(Y + row + ow*32 + ot*16 + q*4) = pk2;
    }
  }

  // --- register epilogue 2: stats via shfl butterfly (width 16)
  float sv[16];
  #pragma unroll
  for (int ot = 0; ot < 2; ++ot)
    #pragma unroll
    for (int r = 0; r < 4; ++r) {
      float a = 0.f, qs = 0.f;
      #pragma unroll
      for (int ns = 0; ns < 8; ++ns) {
        float v = fin[ot][ns][r];
        a += v; qs += v*v;
      }
      sv[ot*4+r] = a; sv[8+ot*4+r] = qs;
    }
  #pragma unroll
  for (int msk = 1; msk < 16; msk <<= 1) {
    #pragma unroll
    for (int i = 0; i < 16; ++i) sv[i] += __shfl_xor(sv[i], msk, 16);
  }
  if (l15 == 0) {
    int slot4 = ((b*128 + x) << 2) | w;   // [0,2048)
    #pragma unroll
    for (int ot = 0; ot < 2; ++ot)
      #pragma unroll
      for (int r = 0; r < 4; ++r) {
        int o = ow*32 + ot*16 + q*4 + r;
        cpart2[((size_t)((t*64 + o)*2 + 0))*2048 + slot4] = sv[ot*4+r];
        cpart2[((size_t)((t*64 + o)*2 + 1))*2048 + slot4] = sv[8+ot*4+r];
      }
  }
}

// ---------------------------------------------------------------------------
// Reduce conv partials -> per-(t,o) scale/shift.  Grid 256 = (t,o).
// ---------------------------------------------------------------------------
__global__ __launch_bounds__(256) void bnparam_kernel(
    const float* __restrict__ cpart2,  // (256,2,2048)
    const float* __restrict__ gam,
    const float* __restrict__ bet,
    float* __restrict__ ss)            // (T*O,2)
{
  const int to = blockIdx.x;
  const int tid = threadIdx.x;
  __shared__ float r1[256], r2[256];
  const float* p1 = cpart2 + (size_t)to*2*2048;
  const float* p2 = p1 + 2048;
  float s1 = 0.f, s2 = 0.f;
  for (int i = tid*4; i < 2048; i += 1024) {
    float4 a = *(const float4*)(p1 + i);
    float4 c = *(const float4*)(p2 + i);
    s1 += a.x + a.y + a.z + a.w;
    s2 += c.x + c.y + c.z + c.w;
  }
  r1[tid] = s1; r2[tid] = s2;
  __syncthreads();
  for (int st = 128; st > 0; st >>= 1) {
    if (tid < st) { r1[tid] += r1[tid+st]; r2[tid] += r2[tid+st]; }
    __syncthreads();
  }
  if (tid == 0) {
    const float inv = 1.f / (float)(BB * NN);
    float mean = r1[0] * inv;
    float var  = r2[0] * inv - mean * mean;
    float sc = gam[to] * rsqrtf(var + EPS_BN);
    ss[to*2 + 0] = sc;
    ss[to*2 + 1] = bet[to] - mean * sc;
  }
}

// ---------------------------------------------------------------------------
// wfuse: fold conv-BN into fusion weights.
//   fbp[o]  = fb[o] + sum_c fw[o,c]*sh[c]
//   FWB[rk*2048 + ow*1024 + ot*512 + l15*32 + q*8 + j] = bf16(fw[o,c]*sc[c])
// 1 block, 256 threads.
// ---------------------------------------------------------------------------
__global__ __launch_bounds__(256) void wfuse_kernel(
    const float* __restrict__ fw,     // (O,256)
    const float* __restrict__ fb,     // (O)
    const float* __restrict__ ss,     // (256,2) sc/sh
    float* __restrict__ fbp,          // (O)
    unsigned short* __restrict__ FWB) // (16384) bf16 fragment-order
{
  const int tid = threadIdx.x;
  {
    int o = tid >> 2, c0 = (tid & 3) * 64;
    float s = 0.f;
    for (int c = c0; c < c0 + 64; ++c)
      s += fw[o*256 + c] * ss[c*2 + 1];
    s += __shfl_xor(s, 1);
    s += __shfl_xor(s, 2);
    if ((tid & 3) == 0) fbp[o] = fb[o] + s;
  }
  for (int e = tid; e < 16384; e += 256) {
    int rk  = e >> 11;
    int ow  = (e >> 10) & 1;
    int ot  = (e >> 9) & 1;
    int l15 = (e >> 5) & 15;
    int cj  = e & 31;                      // q*8 + j
    int o = ow*32 + ot*16 + l15;
    int c = (rk >> 1)*64 + (rk & 1)*32 + cj;
    FWB[e] = f2bf(fw[o*256 + c] * ss[c*2]);
  }
}

// ---------------------------------------------------------------------------
// Fusion: n-tile 128, K=256 in 4 quarter-rounds (r6-proven structure),
// XCD-partitioned grid: batch b's blocks on XCD pair {2b,2b+1} for Y-gather
// L2/L3 locality.  lb(256,4), raw Y gather, FWB fragments, slot stats.
// ---------------------------------------------------------------------------
__global__ __launch_bounds__(256, 4) void fusion_kernel(
    const unsigned short* __restrict__ Y,    // (T,B,N,O) bf16
    const int*   __restrict__ rind,          // (B,N,T)
    const unsigned short* __restrict__ FWB,  // pre-scaled fragment weights
    const float* __restrict__ fbp,           // (O) folded bias
    float* __restrict__ out,                 // (B,O,N) pre-BN
    float* __restrict__ fpart2)              // (O, 2, 4096 slots)
{
  const int flat = blockIdx.x;              // [0,1024)
  const int xcd  = flat & 7;
  const int b    = xcd >> 1;
  const int x    = (xcd & 1) + 2*(flat >> 3);  // [0,256)
  const int n0   = x * 128;
  const int tid = threadIdx.x;
  const int lane = tid & 63;
  const int w    = tid >> 6;
  const int l15  = lane & 15;
  const int q    = lane >> 4;
  const int ow   = w & 1;
  const int nw   = w >> 1;

  __shared__ short zg[128*64];      // exact 128B rows, chunk-XOR swizzled

  // prefetch reindices: thread covers rows n = (tid>>3) + 32*i (all 4 t)
  int4 rg[4];
  #pragma unroll
  for (int i = 0; i < 4; ++i) {
    int n = (tid >> 3) + 32*i;
    rg[i] = *(const int4*)(rind + ((size_t)b*NN + n0 + n)*TT);
  }

  f32x4 fin[2][4];
  #pragma unroll
  for (int ot = 0; ot < 2; ++ot)
    #pragma unroll
    for (int ns = 0; ns < 4; ++ns) fin[ot][ns] = (f32x4){0.f,0.f,0.f,0.f};

  #pragma unroll
  for (int r = 0; r < 4; ++r) {     // K-quarter == t index
    if (r) __syncthreads();
    // stage 128 raw rows of Y[r,b,rn,.] (no conversion)
    #pragma unroll
    for (int i = 0; i < 4; ++i) {
      int u = tid + 256*i;          // < 1024
      int n = u >> 3, s = u & 7;
      int rn = (r == 0) ? rg[i].x : (r == 1) ? rg[i].y
             : (r == 2) ? rg[i].z : rg[i].w;
      int4 raw = *(const int4*)(Y + (((size_t)r*BB + b)*NN + rn)*OO + s*8);
      *(int4*)&zg[(n << 6) + ((s ^ (n & 7)) << 3)] = raw;
    }
    __syncthreads();

    #pragma unroll
    for (int kk = 0; kk < 2; ++kk) {
      int rk = r*2 + kk;
      const unsigned short* wp = FWB + rk*2048 + ow*1024 + (l15*4 + q)*8;
      bf16x8 af[2];
      af[0] = *(const bf16x8*)(wp);
      af[1] = *(const bf16x8*)(wp + 512);
      #pragma unroll
      for (int ns = 0; ns < 4; ++ns) {
        int nl = nw*64 + ns*16 + l15;
        int ch = (kk*4 + q) ^ (nl & 7);
        bf16x8 bfr = *(const bf16x8*)&zg[(nl << 6) + (ch << 3)];
        #pragma unroll
        for (int ot = 0; ot < 2; ++ot)
          fin[ot][ns] = __builtin_amdgcn_mfma_f32_16x16x32_bf16(af[ot], bfr, fin[ot][ns], 0, 0, 0);
      }
    }
  }

  // epilogue: folded bias, coalesced stores, stats butterfly + slot stores
  float sv[16];
  #pragma unroll
  for (int ot = 0; ot < 2; ++ot)
    #pragma unroll
    for (int r2 = 0; r2 < 4; ++r2) {
      int o = ow*32 + ot*16 + q*4 + r2;
      float bias = fbp[o];
      float* dst = out + ((size_t)(b*OO + o))*NN + n0 + nw*64;
      float a = 0.f, qs = 0.f;
      #pragma unroll
      for (int ns = 0; ns < 4; ++ns) {
        float v = fin[ot][ns][r2] + bias;
        dst[ns*16 + l15] = v;
        a += v; qs += v*v;
      }
      sv[ot*4+r2] = a; sv[8+ot*4+r2] = qs;
    }
  #pragma unroll
  for (int msk = 1; msk < 16; msk <<= 1) {
    #pragma unroll
    for (int i = 0; i < 16; ++i) sv[i] += __shfl_xor(sv[i], msk, 16);
  }
  if (l15 == 0) {
    int slot4 = ((b*256 + x) << 2) | w;   // [0,4096)
    #pragma unroll
    for (int ot = 0; ot < 2; ++ot)
      #pragma unroll
      for (int r2 = 0; r2 < 4; ++r2) {
        int o = ow*32 + ot*16 + q*4 + r2;
        fpart2[((size_t)(o*2 + 0))*4096 + slot4] = sv[ot*4+r2];
        fpart2[((size_t)(o*2 + 1))*4096 + slot4] = sv[8+ot*4+r2];
      }
  }
}

// ---------------------------------------------------------------------------
// Fold fusion partials -> per-o scale/shift.  Grid 64 = o.
// ---------------------------------------------------------------------------
__global__ __launch_bounds__(256) void freduce_kernel(
    const float* __restrict__ fpart2,  // (64,2,4096)
    const float* __restrict__ fg,
    const float* __restrict__ fbeta,
    float* __restrict__ fss)
{
  const int o = blockIdx.x;
  const int tid = threadIdx.x;
  __shared__ float r1[256], r2[256];
  const float* p1 = fpart2 + (size_t)o*2*4096;
  const float* p2 = p1 + 4096;
  float s1 = 0.f, s2 = 0.f;
  for (int i = tid*4; i < 4096; i += 1024) {
    float4 a = *(const float4*)(p1 + i);
    float4 c = *(const float4*)(p2 + i);
    s1 += a.x + a.y + a.z + a.w;
    s2 += c.x + c.y + c.z + c.w;
  }
  r1[tid] = s1; r2[tid] = s2;
  __syncthreads();
  for (int st = 128; st > 0; st >>= 1) {
    if (tid < st) { r1[tid] += r1[tid+st]; r2[tid] += r2[tid+st]; }
    __syncthreads();
  }
  if (tid == 0) {
    const float inv = 1.f / (float)(BB * NN);
    float mean = r1[0] * inv;
    float var  = r2[0] * inv - mean * mean;
    float sc = fg[o] * rsqrtf(var + EPS_BN);
    fss[o*2 + 0] = sc;
    fss[o*2 + 1] = fbeta[o] - mean * sc;
  }
}

// ---------------------------------------------------------------------------
// fusion BN + relu, in place (float4 vectorized)
// ---------------------------------------------------------------------------
__global__ __launch_bounds__(256) void final_kernel(
    float* __restrict__ out, const float* __restrict__ fss)
{
  const int base = blockIdx.x * 2048 + threadIdx.x * 4;
  #pragma unroll
  for (int s = 0; s < 2; ++s) {
    int e = base + s * 1024;
    int o2 = (e >> 15) & 63;
    float sc = fss[o2*2 + 0];
    float sh = fss[o2*2 + 1];
    float4 v = *(float4*)(out + e);
    v.x = fmaxf(v.x*sc + sh, 0.f);
    v.y = fmaxf(v.y*sc + sh, 0.f);
    v.z = fmaxf(v.z*sc + sh, 0.f);
    v.w = fmaxf(v.w*sc + sh, 0.f);
    *(float4*)(out + e) = v;
  }
}

// ---------------------------------------------------------------------------
extern "C" void kernel_launch(void* const* d_in, const int* in_sizes, int n_in,
                              void* d_out, int out_size, void* d_ws, size_t ws_size,
                              hipStream_t stream) {
  const float* inp  = (const float*)d_in[0];
  const float* mc   = (const float*)d_in[1];
  const int*   ind  = (const int*)  d_in[2];
  const int*   rind = (const int*)  d_in[3];
  const float* cw   = (const float*)d_in[4];
  const float* bg   = (const float*)d_in[5];
  const float* bb   = (const float*)d_in[6];
  const float* fw   = (const float*)d_in[7];
  const float* fb   = (const float*)d_in[8];
  const float* fg   = (const float*)d_in[9];
  const float* fbt  = (const float*)d_in[10];

  // ws: [0,2048) convss | [2048,2560) fss | [3072,3328) fbp |
  //     [8192, 8192+64MiB) Y | [+2MiB) fpart2 | [+32KiB) FWB
  char* ws = (char*)d_ws;
  float* convss = (float*)(ws + 0);
  float* fss    = (float*)(ws + 2048);
  float* fbp    = (float*)(ws + 3072);
  unsigned short* Y = (unsigned short*)(ws + 8192);          // 67,108,864 B
  float* fpart2 = (float*)(ws + 8192 + 67108864);            // 2 MiB
  unsigned short* FWB = (unsigned short*)(ws + 8192 + 67108864 + 2097152); // 32 KiB

  // scratch in d_out (all dead before fusion writes it):
  char* ob = (char*)d_out;
  unsigned short* xTb = (unsigned short*)ob;                 // 16,777,216 B
  unsigned short* W4  = (unsigned short*)(ob + 16777216);    //    294,912 B
  float* cpart2 = (float*)(ob + 17072128);                   //  4,194,304 B
  int*   indT   = (int*)  (ob + 21266432);                   //  2,097,152 B
  float* mcT    = (float*)(ob + 23363584);                   //  6,291,456 B  (ends 29,655,040 < 32MiB)
  float* out = (float*)d_out;

  prep_kernel<<<2596, 256, 0, stream>>>(inp, xTb, cw, W4, ind, mc, indT, mcT);

  conv_kernel<<<2048, 256, 0, stream>>>(xTb, mcT, indT, W4, Y, cpart2);

  bnparam_kernel<<<256, 256, 0, stream>>>(cpart2, bg, bb, convss);

  wfuse_kernel<<<1, 256, 0, stream>>>(fw, fb, convss, fbp, FWB);

  fusion_kernel<<<1024, 256, 0, stream>>>(Y, rind, FWB, fbp, out, fpart2);

  freduce_kernel<<<OO, 256, 0, stream>>>(fpart2, fg, fbt, fss);

  final_kernel<<<(BB*OO*NN)/2048, 256, 0, stream>>>(out, fss);
}